// Round 1
// baseline (6234.142 us; speedup 1.0000x reference)
//
#include <hip/hip_runtime.h>
#include <hip/hip_bf16.h>

constexpr int N_NODES = 100000;
constexpr int N_EDGES = 1600000;
constexpr int D = 128;
constexpr int N_CLASSES = 64;

// ---------------------------------------------------------------------------
// degree: deg[dst[e]] += 1
// ---------------------------------------------------------------------------
__global__ __launch_bounds__(256) void degree_k(const int* __restrict__ dst,
                                                float* __restrict__ deg) {
    int e = blockIdx.x * 256 + threadIdx.x;
    if (e < N_EDGES) atomicAdd(deg + dst[e], 1.0f);
}

// ---------------------------------------------------------------------------
// scatter: agg[dst[e]][:] += h[src[e]][:]
// 32 threads per edge, each handles one float4 chunk (coalesced within edge).
// ---------------------------------------------------------------------------
__global__ __launch_bounds__(256) void scatter_k(const float* __restrict__ h,
                                                 const int* __restrict__ src,
                                                 const int* __restrict__ dst,
                                                 float* __restrict__ agg) {
    int t = blockIdx.x * 256 + threadIdx.x;   // < N_EDGES*32 = 51.2M, fits int
    int e = t >> 5;
    int c = t & 31;
    if (e >= N_EDGES) return;
    int s = src[e];
    int d = dst[e];
    float4 v = ((const float4*)(h + (size_t)s * D))[c];
    float* a = agg + (size_t)d * D + c * 4;
    atomicAdd(a + 0, v.x);
    atomicAdd(a + 1, v.y);
    atomicAdd(a + 2, v.z);
    atomicAdd(a + 3, v.w);
}

// ---------------------------------------------------------------------------
// fused layer: out[n][j] = act( X[n,:]@Wself[:,j] + (agg[n,:]/deg[n])@Wneigh[:,j] + b[j] )
// 16 nodes per block, 256 threads: thread t -> node (t>>4), outputs j0..j0+PO-1.
// X row and mean row staged in LDS (stride 132 -> conflict-free broadcast).
// Writing out over agg is safe: block stages its rows before writing them.
// ---------------------------------------------------------------------------
template <int DOUT, bool NEIGH, bool RELU>
__global__ __launch_bounds__(256) void layer_k(const float* __restrict__ X,
                                               const float* __restrict__ agg,
                                               const float* __restrict__ deg,
                                               const float* __restrict__ Wself,
                                               const float* __restrict__ Wneigh,
                                               const float* __restrict__ bias,
                                               float* __restrict__ out) {
    __shared__ float xs[16][132];
    __shared__ float ms[16][132];

    const int t = threadIdx.x;
    const int nbase = blockIdx.x * 16;

    // stage 16 rows of X (and mean) into LDS: 512 float4 loads, 2 per thread
    #pragma unroll
    for (int i = 0; i < 2; ++i) {
        int idx4 = t * 2 + i;      // 0..511
        int ni   = idx4 >> 5;      // node within tile
        int c    = idx4 & 31;      // float4 chunk within row
        int node = nbase + ni;
        float4 v = ((const float4*)(X + (size_t)node * D))[c];
        ((float4*)&xs[ni][0])[c] = v;
        if (NEIGH) {
            float inv = 1.0f / fmaxf(deg[node], 1.0f);
            float4 a = ((const float4*)(agg + (size_t)node * D))[c];
            a.x *= inv; a.y *= inv; a.z *= inv; a.w *= inv;
            ((float4*)&ms[ni][0])[c] = a;
        }
    }
    __syncthreads();

    constexpr int PO = DOUT / 16;           // 8 (hidden) or 4 (classes)
    const int ni = t >> 4;
    const int j0 = (t & 15) * PO;

    float acc[PO];
    #pragma unroll
    for (int i = 0; i < PO; ++i) acc[i] = bias[j0 + i];

    #pragma unroll 4
    for (int k = 0; k < D; ++k) {
        float xv = xs[ni][k];
        const float* wsrow = Wself + (size_t)k * DOUT + j0;
        #pragma unroll
        for (int i = 0; i < PO; ++i) acc[i] += xv * wsrow[i];
        if (NEIGH) {
            float mv = ms[ni][k];
            const float* wnrow = Wneigh + (size_t)k * DOUT + j0;
            #pragma unroll
            for (int i = 0; i < PO; ++i) acc[i] += mv * wnrow[i];
        }
    }

    if (RELU) {
        #pragma unroll
        for (int i = 0; i < PO; ++i) acc[i] = fmaxf(acc[i], 0.0f);
    }

    float* orow = out + (size_t)(nbase + ni) * DOUT + j0;
    float4* o4 = (float4*)orow;
    #pragma unroll
    for (int i = 0; i < PO / 4; ++i) {
        float4 v = make_float4(acc[i * 4 + 0], acc[i * 4 + 1],
                               acc[i * 4 + 2], acc[i * 4 + 3]);
        o4[i] = v;
    }
}

// ---------------------------------------------------------------------------
extern "C" void kernel_launch(void* const* d_in, const int* in_sizes, int n_in,
                              void* d_out, int out_size, void* d_ws, size_t ws_size,
                              hipStream_t stream) {
    const float* feat   = (const float*)d_in[0];
    const int*   src    = (const int*)d_in[1];
    const int*   dst    = (const int*)d_in[2];
    const float* Wself1 = (const float*)d_in[3];
    const float* Wneigh1= (const float*)d_in[4];
    const float* b1     = (const float*)d_in[5];
    const float* Wself2 = (const float*)d_in[6];
    const float* Wneigh2= (const float*)d_in[7];
    const float* b2     = (const float*)d_in[8];
    const float* Wout   = (const float*)d_in[9];
    const float* bout   = (const float*)d_in[10];
    float* out = (float*)d_out;

    // workspace layout (all 16B aligned):
    //   deg : N_NODES floats            (400 KB)
    //   agg : N_NODES*D floats          (51.2 MB)   also reused as h2
    //   h1  : N_NODES*D floats          (51.2 MB)
    float* deg = (float*)d_ws;
    float* agg = deg + N_NODES;
    float* h1  = agg + (size_t)N_NODES * D;

    const int edge_blocks    = (N_EDGES + 255) / 256;          // 6250
    const int scatter_blocks = (N_EDGES * 32 + 255) / 256;     // 200000
    const int node_blocks    = N_NODES / 16;                   // 6250

    // zero deg + agg (contiguous)
    hipMemsetAsync(deg, 0, (size_t)(N_NODES + (size_t)N_NODES * D) * sizeof(float), stream);

    degree_k<<<edge_blocks, 256, 0, stream>>>(dst, deg);

    // layer 1
    scatter_k<<<scatter_blocks, 256, 0, stream>>>(feat, src, dst, agg);
    layer_k<D, true, true><<<node_blocks, 256, 0, stream>>>(
        feat, agg, deg, Wself1, Wneigh1, b1, h1);

    // layer 2 (output written in place over agg -> becomes h2)
    hipMemsetAsync(agg, 0, (size_t)N_NODES * D * sizeof(float), stream);
    scatter_k<<<scatter_blocks, 256, 0, stream>>>(h1, src, dst, agg);
    layer_k<D, true, true><<<node_blocks, 256, 0, stream>>>(
        h1, agg, deg, Wself2, Wneigh2, b2, agg);

    // output projection
    layer_k<N_CLASSES, false, false><<<node_blocks, 256, 0, stream>>>(
        agg, nullptr, nullptr, Wout, nullptr, bout, out);
}

// Round 2
// 1288.575 us; speedup vs baseline: 4.8380x; 4.8380x over previous
//
#include <hip/hip_runtime.h>
#include <hip/hip_bf16.h>

constexpr int N_NODES = 100000;
constexpr int N_EDGES = 1600000;
constexpr int D = 128;
constexpr int N_CLASSES = 64;

constexpr int SCAN_B = 256;
constexpr int NB_SCAN = (N_NODES + SCAN_B - 1) / SCAN_B;   // 391

// ---------------------------------------------------------------------------
// degree count (int atomics on 100k counters)
// ---------------------------------------------------------------------------
__global__ __launch_bounds__(256) void deg_count_k(const int* __restrict__ dst,
                                                   int* __restrict__ degi) {
    int e = blockIdx.x * 256 + threadIdx.x;
    if (e < N_EDGES) atomicAdd(degi + dst[e], 1);
}

// ---------------------------------------------------------------------------
// 3-kernel exclusive scan of degi -> rowptr (and cursor = rowptr copy)
// ---------------------------------------------------------------------------
__global__ __launch_bounds__(256) void scan1_k(const int* __restrict__ degi,
                                               int* __restrict__ bsum) {
    __shared__ int s[256];
    int t = threadIdx.x;
    int i = blockIdx.x * 256 + t;
    s[t] = (i < N_NODES) ? degi[i] : 0;
    __syncthreads();
    #pragma unroll
    for (int off = 128; off > 0; off >>= 1) {
        if (t < off) s[t] += s[t + off];
        __syncthreads();
    }
    if (t == 0) bsum[blockIdx.x] = s[0];
}

__global__ __launch_bounds__(512) void scan2_k(int* __restrict__ bsum) {
    __shared__ int s[512];
    int t = threadIdx.x;
    s[t] = (t < NB_SCAN) ? bsum[t] : 0;
    __syncthreads();
    #pragma unroll
    for (int off = 1; off < 512; off <<= 1) {
        int v = (t >= off) ? s[t - off] : 0;
        __syncthreads();
        s[t] += v;
        __syncthreads();
    }
    if (t < NB_SCAN) bsum[t] = (t == 0) ? 0 : s[t - 1];   // exclusive
}

__global__ __launch_bounds__(256) void scan3_k(const int* __restrict__ degi,
                                               const int* __restrict__ bsum,
                                               int* __restrict__ rowptr,
                                               int* __restrict__ cursor) {
    __shared__ int s[256];
    int t = threadIdx.x;
    int i = blockIdx.x * 256 + t;
    int v = (i < N_NODES) ? degi[i] : 0;
    s[t] = v;
    __syncthreads();
    #pragma unroll
    for (int off = 1; off < 256; off <<= 1) {
        int u = (t >= off) ? s[t - off] : 0;
        __syncthreads();
        s[t] += u;
        __syncthreads();
    }
    if (i < N_NODES) {
        int p = bsum[blockIdx.x] + s[t] - v;   // exclusive prefix
        rowptr[i] = p;
        cursor[i] = p;
        if (i == N_NODES - 1) rowptr[N_NODES] = p + v;   // == N_EDGES
    }
}

// ---------------------------------------------------------------------------
// bucket fill: csr_src[rowptr[dst]+k] = src   (order within bucket arbitrary)
// ---------------------------------------------------------------------------
__global__ __launch_bounds__(256) void fill_k(const int* __restrict__ src,
                                              const int* __restrict__ dst,
                                              int* __restrict__ cursor,
                                              int* __restrict__ csr_src) {
    int e = blockIdx.x * 256 + threadIdx.x;
    if (e >= N_EDGES) return;
    int pos = atomicAdd(cursor + dst[e], 1);
    csr_src[pos] = src[e];
}

// ---------------------------------------------------------------------------
// gather + mean: aggmean[n][:] = (1/max(deg,1)) * sum_{e in N(n)} h[csr_src[e]][:]
// one wave per node; lane handles a float2 column. No atomics.
// ---------------------------------------------------------------------------
__global__ __launch_bounds__(256) void gather_k(const float* __restrict__ h,
                                                const int* __restrict__ rowptr,
                                                const int* __restrict__ csr_src,
                                                float* __restrict__ aggmean) {
    int node = (blockIdx.x * 256 + threadIdx.x) >> 6;
    int lane = threadIdx.x & 63;
    if (node >= N_NODES) return;
    int beg = rowptr[node];
    int end = rowptr[node + 1];

    float2 acc0 = {0.f, 0.f}, acc1 = {0.f, 0.f};
    int idx = beg;
    for (; idx + 1 < end; idx += 2) {
        int s0 = csr_src[idx];
        int s1 = csr_src[idx + 1];
        float2 v0 = ((const float2*)(h + (size_t)s0 * D))[lane];
        float2 v1 = ((const float2*)(h + (size_t)s1 * D))[lane];
        acc0.x += v0.x; acc0.y += v0.y;
        acc1.x += v1.x; acc1.y += v1.y;
    }
    if (idx < end) {
        int s0 = csr_src[idx];
        float2 v0 = ((const float2*)(h + (size_t)s0 * D))[lane];
        acc0.x += v0.x; acc0.y += v0.y;
    }
    float inv = 1.0f / fmaxf((float)(end - beg), 1.0f);
    float2 m = {(acc0.x + acc1.x) * inv, (acc0.y + acc1.y) * inv};
    ((float2*)(aggmean + (size_t)node * D))[lane] = m;
}

// ---------------------------------------------------------------------------
// fused layer: out[n][j] = act( X[n,:]@Wself[:,j] + mean[n,:]@Wneigh[:,j] + b[j] )
// mean is already divided by degree (gather_k did it).
// ---------------------------------------------------------------------------
template <int DOUT, bool NEIGH, bool RELU>
__global__ __launch_bounds__(256) void layer_k(const float* __restrict__ X,
                                               const float* __restrict__ mean,
                                               const float* __restrict__ Wself,
                                               const float* __restrict__ Wneigh,
                                               const float* __restrict__ bias,
                                               float* __restrict__ out) {
    __shared__ float xs[16][132];
    __shared__ float ms[16][132];

    const int t = threadIdx.x;
    const int nbase = blockIdx.x * 16;

    #pragma unroll
    for (int i = 0; i < 2; ++i) {
        int idx4 = t * 2 + i;      // 0..511
        int ni   = idx4 >> 5;
        int c    = idx4 & 31;
        int node = nbase + ni;
        float4 v = ((const float4*)(X + (size_t)node * D))[c];
        ((float4*)&xs[ni][0])[c] = v;
        if (NEIGH) {
            float4 a = ((const float4*)(mean + (size_t)node * D))[c];
            ((float4*)&ms[ni][0])[c] = a;
        }
    }
    __syncthreads();

    constexpr int PO = DOUT / 16;           // 8 (hidden) or 4 (classes)
    const int ni = t >> 4;
    const int j0 = (t & 15) * PO;

    float acc[PO];
    #pragma unroll
    for (int i = 0; i < PO; ++i) acc[i] = bias[j0 + i];

    #pragma unroll 4
    for (int k = 0; k < D; ++k) {
        float xv = xs[ni][k];
        const float* wsrow = Wself + (size_t)k * DOUT + j0;
        #pragma unroll
        for (int i = 0; i < PO; ++i) acc[i] += xv * wsrow[i];
        if (NEIGH) {
            float mv = ms[ni][k];
            const float* wnrow = Wneigh + (size_t)k * DOUT + j0;
            #pragma unroll
            for (int i = 0; i < PO; ++i) acc[i] += mv * wnrow[i];
        }
    }

    if (RELU) {
        #pragma unroll
        for (int i = 0; i < PO; ++i) acc[i] = fmaxf(acc[i], 0.0f);
    }

    float* orow = out + (size_t)(nbase + ni) * DOUT + j0;
    float4* o4 = (float4*)orow;
    #pragma unroll
    for (int i = 0; i < PO / 4; ++i) {
        o4[i] = make_float4(acc[i * 4 + 0], acc[i * 4 + 1],
                            acc[i * 4 + 2], acc[i * 4 + 3]);
    }
}

// ---------------------------------------------------------------------------
extern "C" void kernel_launch(void* const* d_in, const int* in_sizes, int n_in,
                              void* d_out, int out_size, void* d_ws, size_t ws_size,
                              hipStream_t stream) {
    const float* feat   = (const float*)d_in[0];
    const int*   src    = (const int*)d_in[1];
    const int*   dst    = (const int*)d_in[2];
    const float* Wself1 = (const float*)d_in[3];
    const float* Wneigh1= (const float*)d_in[4];
    const float* b1     = (const float*)d_in[5];
    const float* Wself2 = (const float*)d_in[6];
    const float* Wneigh2= (const float*)d_in[7];
    const float* b2     = (const float*)d_in[8];
    const float* Wout   = (const float*)d_in[9];
    const float* bout   = (const float*)d_in[10];
    float* out = (float*)d_out;

    // workspace layout (16B-aligned chunks):
    int*   degi    = (int*)d_ws;                      // 100000 ints
    int*   rowptr  = degi + N_NODES;                  // 100004 ints (N+1, padded)
    int*   cursor  = rowptr + (N_NODES + 4);          // 100000 ints
    int*   bsum    = cursor + N_NODES;                // 512 ints
    int*   csr_src = bsum + 512;                      // 1.6M ints
    float* agg     = (float*)(csr_src + N_EDGES);     // 12.8M floats
    float* h1      = agg + (size_t)N_NODES * D;       // 12.8M floats

    const int edge_blocks   = (N_EDGES + 255) / 256;          // 6250
    const int node_blocks   = N_NODES / 16;                   // 6250
    const int gather_blocks = (N_NODES * 64 + 255) / 256;     // 25000

    // ---- build CSR (by destination) ----
    hipMemsetAsync(degi, 0, N_NODES * sizeof(int), stream);
    deg_count_k<<<edge_blocks, 256, 0, stream>>>(dst, degi);
    scan1_k<<<NB_SCAN, 256, 0, stream>>>(degi, bsum);
    scan2_k<<<1, 512, 0, stream>>>(bsum);
    scan3_k<<<NB_SCAN, 256, 0, stream>>>(degi, bsum, rowptr, cursor);
    fill_k<<<edge_blocks, 256, 0, stream>>>(src, dst, cursor, csr_src);

    // ---- layer 1 ----
    gather_k<<<gather_blocks, 256, 0, stream>>>(feat, rowptr, csr_src, agg);
    layer_k<D, true, true><<<node_blocks, 256, 0, stream>>>(
        feat, agg, Wself1, Wneigh1, b1, h1);

    // ---- layer 2 (h2 written in place over agg) ----
    gather_k<<<gather_blocks, 256, 0, stream>>>(h1, rowptr, csr_src, agg);
    layer_k<D, true, true><<<node_blocks, 256, 0, stream>>>(
        h1, agg, Wself2, Wneigh2, b2, agg);

    // ---- output projection ----
    layer_k<N_CLASSES, false, false><<<node_blocks, 256, 0, stream>>>(
        agg, nullptr, Wout, nullptr, bout, out);
}

// Round 3
// 487.903 us; speedup vs baseline: 12.7774x; 2.6410x over previous
//
#include <hip/hip_runtime.h>
#include <hip/hip_bf16.h>

constexpr int N_NODES = 100000;
constexpr int N_EDGES = 1600000;
constexpr int D = 128;
constexpr int N_CLASSES = 64;

constexpr int SCAN_B = 256;
constexpr int NB_SCAN = (N_NODES + SCAN_B - 1) / SCAN_B;   // 391

typedef __attribute__((ext_vector_type(8))) short short8;
typedef __attribute__((ext_vector_type(4))) float f32x4;

static __device__ __forceinline__ float bf2f(unsigned int lo16) {
    unsigned int x = lo16 << 16;
    return __builtin_bit_cast(float, x);
}
static __device__ __forceinline__ unsigned short f2bf(float f) {
    unsigned int x = __builtin_bit_cast(unsigned int, f);
    x += 0x7fffu + ((x >> 16) & 1u);          // RNE
    return (unsigned short)(x >> 16);
}

// ---------------------------------------------------------------------------
// CSR build (by destination)
// ---------------------------------------------------------------------------
__global__ __launch_bounds__(256) void deg_count_k(const int* __restrict__ dst,
                                                   int* __restrict__ degi) {
    int e = blockIdx.x * 256 + threadIdx.x;
    if (e < N_EDGES) atomicAdd(degi + dst[e], 1);
}

__global__ __launch_bounds__(256) void scan1_k(const int* __restrict__ degi,
                                               int* __restrict__ bsum) {
    __shared__ int s[256];
    int t = threadIdx.x;
    int i = blockIdx.x * 256 + t;
    s[t] = (i < N_NODES) ? degi[i] : 0;
    __syncthreads();
    #pragma unroll
    for (int off = 128; off > 0; off >>= 1) {
        if (t < off) s[t] += s[t + off];
        __syncthreads();
    }
    if (t == 0) bsum[blockIdx.x] = s[0];
}

__global__ __launch_bounds__(512) void scan2_k(int* __restrict__ bsum) {
    __shared__ int s[512];
    int t = threadIdx.x;
    s[t] = (t < NB_SCAN) ? bsum[t] : 0;
    __syncthreads();
    #pragma unroll
    for (int off = 1; off < 512; off <<= 1) {
        int v = (t >= off) ? s[t - off] : 0;
        __syncthreads();
        s[t] += v;
        __syncthreads();
    }
    if (t < NB_SCAN) bsum[t] = (t == 0) ? 0 : s[t - 1];   // exclusive
}

__global__ __launch_bounds__(256) void scan3_k(const int* __restrict__ degi,
                                               const int* __restrict__ bsum,
                                               int* __restrict__ rowptr,
                                               int* __restrict__ cursor) {
    __shared__ int s[256];
    int t = threadIdx.x;
    int i = blockIdx.x * 256 + t;
    int v = (i < N_NODES) ? degi[i] : 0;
    s[t] = v;
    __syncthreads();
    #pragma unroll
    for (int off = 1; off < 256; off <<= 1) {
        int u = (t >= off) ? s[t - off] : 0;
        __syncthreads();
        s[t] += u;
        __syncthreads();
    }
    if (i < N_NODES) {
        int p = bsum[blockIdx.x] + s[t] - v;
        rowptr[i] = p;
        cursor[i] = p;
        if (i == N_NODES - 1) rowptr[N_NODES] = p + v;
    }
}

__global__ __launch_bounds__(256) void fill_k(const int* __restrict__ src,
                                              const int* __restrict__ dst,
                                              int* __restrict__ cursor,
                                              int* __restrict__ csr_src) {
    int e = blockIdx.x * 256 + threadIdx.x;
    if (e >= N_EDGES) return;
    int pos = atomicAdd(cursor + dst[e], 1);
    csr_src[pos] = src[e];
}

// ---------------------------------------------------------------------------
// feat fp32 -> bf16 into Xcat1 self half (cols 0..127 of 256-wide rows)
// ---------------------------------------------------------------------------
__global__ __launch_bounds__(256) void cvt_feat_k(const float* __restrict__ feat,
                                                  unsigned short* __restrict__ xcat) {
    int i = blockIdx.x * 256 + threadIdx.x;      // one float4 chunk, 3.2M total
    if (i >= N_NODES * (D / 4)) return;
    float4 v = ((const float4*)feat)[i];
    ushort4 r;
    r.x = f2bf(v.x); r.y = f2bf(v.y); r.z = f2bf(v.z); r.w = f2bf(v.w);
    int node = i >> 5;                            // 32 chunks per node
    int c = i & 31;
    *(ushort4*)(xcat + (size_t)node * 256 + c * 4) = r;
}

// ---------------------------------------------------------------------------
// pack W (fp32, rows = K_TOT: first 128 from Wa, rest from Wb) into MFMA
// B-fragment order: wp[((kstep*NCT+ct)*64 + lane)*8 + j]
//                 = W[kstep*32 + (lane>>4)*8 + j][ct*16 + (lane&15)]
// ---------------------------------------------------------------------------
template <int K_TOT, int DOUT>
__global__ __launch_bounds__(64) void packW_k(const float* __restrict__ Wa,
                                              const float* __restrict__ Wb,
                                              unsigned short* __restrict__ wp) {
    constexpr int NCT = DOUT / 16;
    int kstep = blockIdx.x / NCT;
    int ct = blockIdx.x % NCT;
    int lane = threadIdx.x;
    int col = ct * 16 + (lane & 15);
    int kbase = kstep * 32 + (lane >> 4) * 8;
    unsigned short r[8];
    #pragma unroll
    for (int j = 0; j < 8; ++j) {
        int k = kbase + j;
        float w = (k < 128) ? Wa[(size_t)k * DOUT + col]
                            : Wb[(size_t)(k - 128) * DOUT + col];
        r[j] = f2bf(w);
    }
    *(short8*)(wp + ((size_t)((kstep * NCT + ct) * 64 + lane)) * 8) =
        *(const short8*)r;
}

// ---------------------------------------------------------------------------
// gather+mean in bf16: mean over in-neighbors of xcat[:,0:128] -> xcat[:,128:256]
// one wave per node, lane owns 2 columns. fp32 accumulation.
// ---------------------------------------------------------------------------
__global__ __launch_bounds__(256) void gather_k(unsigned short* __restrict__ xcat,
                                                const int* __restrict__ rowptr,
                                                const int* __restrict__ csr_src) {
    int node = (blockIdx.x * 256 + threadIdx.x) >> 6;
    int lane = threadIdx.x & 63;
    if (node >= N_NODES) return;
    int beg = rowptr[node];
    int end = rowptr[node + 1];

    float a0 = 0.f, a1 = 0.f, b0 = 0.f, b1 = 0.f;
    int e = beg;
    for (; e + 1 < end; e += 2) {
        int s0 = csr_src[e];
        int s1 = csr_src[e + 1];
        unsigned int u0 = *(const unsigned int*)(xcat + (size_t)s0 * 256 + lane * 2);
        unsigned int u1 = *(const unsigned int*)(xcat + (size_t)s1 * 256 + lane * 2);
        a0 += bf2f(u0 & 0xffffu); a1 += bf2f(u0 >> 16);
        b0 += bf2f(u1 & 0xffffu); b1 += bf2f(u1 >> 16);
    }
    if (e < end) {
        int s0 = csr_src[e];
        unsigned int u0 = *(const unsigned int*)(xcat + (size_t)s0 * 256 + lane * 2);
        a0 += bf2f(u0 & 0xffffu); a1 += bf2f(u0 >> 16);
    }
    float inv = 1.0f / fmaxf((float)(end - beg), 1.0f);
    unsigned int o = ((unsigned int)f2bf((a1 + b1) * inv) << 16) |
                     (unsigned int)f2bf((a0 + b0) * inv);
    *(unsigned int*)(xcat + (size_t)node * 256 + 128 + lane * 2) = o;
}

// ---------------------------------------------------------------------------
// MFMA GEMM: C[M x DOUT] = act(A[M x K_TOT] @ W + bias)
// A bf16 row-major (lda elems); W pre-packed; 4 waves/block, wave = 16 rows.
// ---------------------------------------------------------------------------
template <int K_TOT, int DOUT, bool RELU, bool BF16OUT>
__global__ __launch_bounds__(256) void gemm_k(const unsigned short* __restrict__ A,
                                              int lda,
                                              const unsigned short* __restrict__ Wp,
                                              const float* __restrict__ bias,
                                              void* __restrict__ Cout, int ldc) {
    constexpr int NCT = DOUT / 16;
    constexpr int KST = K_TOT / 32;
    const int wid = threadIdx.x >> 6;
    const int lane = threadIdx.x & 63;
    const int row0 = blockIdx.x * 64 + wid * 16;
    if (row0 >= N_NODES) return;

    const unsigned short* arow =
        A + (size_t)(row0 + (lane & 15)) * lda + (lane >> 4) * 8;
    const short8* wp8 = (const short8*)Wp;

    f32x4 acc[NCT];
    #pragma unroll
    for (int ct = 0; ct < NCT; ++ct) acc[ct] = {0.f, 0.f, 0.f, 0.f};

    #pragma unroll
    for (int ks = 0; ks < KST; ++ks) {
        short8 af = *(const short8*)(arow + ks * 32);
        #pragma unroll
        for (int ct = 0; ct < NCT; ++ct) {
            short8 bf = wp8[(ks * NCT + ct) * 64 + lane];
            acc[ct] = __builtin_amdgcn_mfma_f32_16x16x32_bf16(af, bf, acc[ct], 0, 0, 0);
        }
    }

    const int r_hi = lane >> 4;      // row = row0 + r_hi*4 + j
    const int col0 = lane & 15;
    #pragma unroll
    for (int ct = 0; ct < NCT; ++ct) {
        float bv = bias[ct * 16 + col0];
        #pragma unroll
        for (int j = 0; j < 4; ++j) {
            float v = acc[ct][j] + bv;
            if (RELU) v = fmaxf(v, 0.f);
            size_t off = (size_t)(row0 + r_hi * 4 + j) * ldc + ct * 16 + col0;
            if (BF16OUT) ((unsigned short*)Cout)[off] = f2bf(v);
            else         ((float*)Cout)[off] = v;
        }
    }
}

// ---------------------------------------------------------------------------
extern "C" void kernel_launch(void* const* d_in, const int* in_sizes, int n_in,
                              void* d_out, int out_size, void* d_ws, size_t ws_size,
                              hipStream_t stream) {
    const float* feat   = (const float*)d_in[0];
    const int*   src    = (const int*)d_in[1];
    const int*   dst    = (const int*)d_in[2];
    const float* Wself1 = (const float*)d_in[3];
    const float* Wneigh1= (const float*)d_in[4];
    const float* b1     = (const float*)d_in[5];
    const float* Wself2 = (const float*)d_in[6];
    const float* Wneigh2= (const float*)d_in[7];
    const float* b2     = (const float*)d_in[8];
    const float* Wout   = (const float*)d_in[9];
    const float* bout   = (const float*)d_in[10];
    float* out = (float*)d_out;

    // workspace layout (all segment starts 16B-aligned):
    int* degi    = (int*)d_ws;                       // 100000
    int* rowptr  = degi + N_NODES;                   // 100004
    int* cursor  = rowptr + (N_NODES + 4);           // 100000
    int* bsum    = cursor + N_NODES;                 // 512
    int* csr_src = bsum + 512;                       // 1.6M
    unsigned short* xcat1 = (unsigned short*)(csr_src + N_EDGES); // 100000*256
    unsigned short* xcat2 = xcat1 + (size_t)N_NODES * 256;        // 100000*256
    unsigned short* wp1   = xcat2 + (size_t)N_NODES * 256;        // 256*128
    unsigned short* wp2   = wp1 + 256 * 128;
    unsigned short* wpo   = wp2 + 256 * 128;                      // 128*64
    unsigned short* h2    = xcat1;   // alias over dead xcat1 (layer-2 output)

    const int edge_blocks   = (N_EDGES + 255) / 256;          // 6250
    const int gather_blocks = (N_NODES * 64 + 255) / 256;     // 25000
    const int cvt_blocks    = (N_NODES * (D / 4) + 255) / 256;// 12500
    const int gemm_blocks   = (N_NODES + 63) / 64;            // 1563

    // ---- CSR build ----
    hipMemsetAsync(degi, 0, N_NODES * sizeof(int), stream);
    deg_count_k<<<edge_blocks, 256, 0, stream>>>(dst, degi);
    scan1_k<<<NB_SCAN, 256, 0, stream>>>(degi, bsum);
    scan2_k<<<1, 512, 0, stream>>>(bsum);
    scan3_k<<<NB_SCAN, 256, 0, stream>>>(degi, bsum, rowptr, cursor);
    fill_k<<<edge_blocks, 256, 0, stream>>>(src, dst, cursor, csr_src);

    // ---- weight packing + feat conversion ----
    cvt_feat_k<<<cvt_blocks, 256, 0, stream>>>(feat, xcat1);
    packW_k<256, 128><<<8 * 8, 64, 0, stream>>>(Wself1, Wneigh1, wp1);
    packW_k<256, 128><<<8 * 8, 64, 0, stream>>>(Wself2, Wneigh2, wp2);
    packW_k<128, 64><<<4 * 4, 64, 0, stream>>>(Wout, nullptr, wpo);

    // ---- layer 1 ----
    gather_k<<<gather_blocks, 256, 0, stream>>>(xcat1, rowptr, csr_src);
    gemm_k<256, 128, true, true><<<gemm_blocks, 256, 0, stream>>>(
        xcat1, 256, wp1, b1, xcat2, 256);

    // ---- layer 2 ----
    gather_k<<<gather_blocks, 256, 0, stream>>>(xcat2, rowptr, csr_src);
    gemm_k<256, 128, true, true><<<gemm_blocks, 256, 0, stream>>>(
        xcat2, 256, wp2, b2, h2, 128);

    // ---- output projection (fp32 out) ----
    gemm_k<128, 64, false, false><<<gemm_blocks, 256, 0, stream>>>(
        h2, 128, wpo, bout, out, 64);
}